// Round 2
// baseline (10828.491 us; speedup 1.0000x reference)
//
#include <hip/hip_runtime.h>

// LSTM b=32, t=1024, din=512, hid=1024. Persistent cooperative kernel:
// 128 blocks x 512 threads (8 waves), each block owns 8 hidden units.
//
// R5: (a) weights live in REGISTERS for all 1024 steps (wb[8][2] short8 per
// wave) -> ldsW eliminated (was the SQ_LDS_BANK_CONFLICT source and per-step
// LDS traffic). (b) cross-wave K-reduction via ds_add_f32 into a single
// bias-initialized accumulator (2 ping-pong 32x33 f32 buffers); only wave 0
// reads gates, does ALL pointwise (4 outputs/lane) and publishes h+flag
// IMMEDIATELY -> one barrier per step. Deadlock-free: publish is not behind
// any barrier that transitively waits on other blocks (linear chain over t).
// (c) init_h flag-zero bug fixed (R4 zeroed NBLK*4 of NBLK*16 ints -> stale
// flags let 3/4 of waits be skipped on timed runs).

#define T_STEPS 1024
#define BATCH   32
#define DIN     512
#define HID     1024
#define KTOT    1536
#define NBLK    128
#define REDSTR  33            // padded fp32 accumulator row stride (2-way max on reads)
#define REDCELLS (32*REDSTR)  // 1056 floats per buffer
#define FLAGSTR 16            // ints per flag (64B exclusive line)

typedef __attribute__((ext_vector_type(8))) short  short8;
typedef __attribute__((ext_vector_type(4))) float  floatx4;
typedef __attribute__((ext_vector_type(4))) unsigned short ushort4_;
typedef __attribute__((ext_vector_type(2))) unsigned int   uint2_;

#define MFMA16(a,b,c) __builtin_amdgcn_mfma_f32_16x16x32_bf16(a, b, c, 0, 0, 0)

__device__ __forceinline__ unsigned short f2bf(float f) {
    unsigned u = __builtin_bit_cast(unsigned, f);
    u += 0x7FFFu + ((u >> 16) & 1u);
    return (unsigned short)(u >> 16);
}
__device__ __forceinline__ float sigf(float x) { return 1.f / (1.f + __expf(-x)); }
__device__ __forceinline__ float tanh_fast(float x) {
    float e = __expf(2.f * x);
    return 1.f - 2.f / (e + 1.f);
}
__device__ __forceinline__ void lds_add(float* p, float v) {
    __hip_atomic_fetch_add(p, v, __ATOMIC_RELAXED, __HIP_MEMORY_SCOPE_WORKGROUP);
}

// ---- device-scope (L3 coherence point) access helpers: sc1 ----
__device__ __forceinline__ floatx4 coh_load16(const void* p) {
    floatx4 v;
    asm volatile("global_load_dwordx4 %0, %1, off sc1" : "=v"(v) : "v"(p));
    return v;
}
__device__ __forceinline__ int coh_load4(const void* p) {
    int v;
    asm volatile("global_load_dword %0, %1, off sc1\n\ts_waitcnt vmcnt(0)"
                 : "=v"(v) : "v"(p) : "memory");
    return v;
}
__device__ __forceinline__ void coh_store8(void* p, uint2_ v) {
    asm volatile("global_store_dwordx2 %0, %1, off sc1" :: "v"(p), "v"(v) : "memory");
}
__device__ __forceinline__ void coh_store4(void* p, int v) {
    asm volatile("global_store_dword %0, %1, off sc1" :: "v"(p), "v"(v) : "memory");
}
__device__ __forceinline__ void wait_vm0() {
    asm volatile("s_waitcnt vmcnt(0)" ::: "memory");
}

// ---- prep: kernel [1536][4096] fp32 -> wt [4096 cols][1536 k] bf16 (transposed) ----
__global__ __launch_bounds__(256) void prep_wt(const float* __restrict__ kern,
                                               unsigned short* __restrict__ wt) {
    __shared__ unsigned short tile[64][72];
    const int c0 = (blockIdx.x & 63) * 64;
    const int k0 = (blockIdx.x >> 6) * 64;
    const int cl = threadIdx.x & 63;
    const int kg = threadIdx.x >> 6;
    #pragma unroll
    for (int i = 0; i < 16; ++i) {
        int kl = kg * 16 + i;
        tile[cl][kl] = f2bf(kern[(k0 + kl) * 4096 + c0 + cl]);
    }
    __syncthreads();
    #pragma unroll
    for (int i = 0; i < 16; ++i) {
        int cc = kg * 16 + i;
        wt[(size_t)(c0 + cc) * KTOT + k0 + cl] = tile[cc][cl];
    }
}

// ---- prep: x [32][1024][512] fp32 -> xT [1024][32][512] bf16 ----
__global__ __launch_bounds__(256) void prep_x(const float* __restrict__ x,
                                              unsigned short* __restrict__ xT) {
    const int row = blockIdx.x * 2 + (threadIdx.x >> 7);
    const int l   = threadIdx.x & 127;
    const int b = row >> 10, t = row & 1023;
    float4 v = ((const float4*)(x + (size_t)row * DIN))[l];
    ushort4_ o;
    o.x = f2bf(v.x); o.y = f2bf(v.y); o.z = f2bf(v.z); o.w = f2bf(v.w);
    *(ushort4_*)(xT + ((size_t)t * BATCH + b) * DIN + l * 4) = o;
}

// ---- prep: h0 -> hbuf[0] per-block layout [blk][batch][unit]; zero ALL flags ----
__global__ __launch_bounds__(256) void init_h(const float* __restrict__ h_init,
                                              unsigned short* __restrict__ hbuf,
                                              int* __restrict__ flags) {
    if (blockIdx.x == 32) {
        for (int i = threadIdx.x; i < NBLK * FLAGSTR; i += 256) flags[i] = 0;
        return;
    }
    const int p0 = blockIdx.x * 4;
    const int u = threadIdx.x & 7;
    #pragma unroll
    for (int j = 0; j < 4; ++j) {
        const int p = p0 + j;
        hbuf[p * 256 + threadIdx.x] = f2bf(h_init[p * 8 + u]);
    }
}

// ---- persistent LSTM ----
__global__ __launch_bounds__(512, 2) void lstm_persist(
    const unsigned short* __restrict__ wt,   // [4096][1536] bf16
    const unsigned short* __restrict__ xT,   // [1024][32][512] bf16
    unsigned short* __restrict__ hbuf,       // [2][128 blk][32 b][8 u] bf16
    int* __restrict__ flags,                 // [128*FLAGSTR]
    const float* __restrict__ bias,          // [4096]
    float* __restrict__ out)                 // [32][1024][1024] fp32
{
    __shared__ float red[2][REDCELLS];       // bias-initialized gate accumulators

    const int bk   = blockIdx.x;
    const int tid  = threadIdx.x;
    const int wave = tid >> 6;
    const int lane = tid & 63;
    const int lrow = lane & 15;
    const int kq   = lane >> 4;
    const bool isG = wave < 4;
    const int  sl  = wave & 3;

    // ---- persistent weight fragments in registers (constant across t) ----
    short8 wb[8][2];
    if (isG) {
        #pragma unroll
        for (int i = 0; i < 4; ++i) {
            const int k = sl * 128 + i * 32 + kq * 8;
            #pragma unroll
            for (int c = 0; c < 2; ++c) {
                const int cl = lrow + c * 16;
                const int gcol = (cl >> 3) * HID + bk * 8 + (cl & 7);
                wb[i][c] = *(const short8*)(wt + (size_t)gcol * KTOT + k);
            }
        }
    } else {
        #pragma unroll
        for (int i = 0; i < 8; ++i) {
            const int k = 512 + sl * 256 + i * 32 + kq * 8;
            #pragma unroll
            for (int c = 0; c < 2; ++c) {
                const int cl = lrow + c * 16;
                const int gcol = (cl >> 3) * HID + bk * 8 + (cl & 7);
                wb[i][c] = *(const short8*)(wt + (size_t)gcol * KTOT + k);
            }
        }
    }

    // wave0 pointwise mapping: lane -> (batch pb, units ju..ju+3)
    const int pb = lane & 31;
    const int ju = (lane >> 5) * 4;
    float bias_r[4][4];
    float c_st[4] = {0.f, 0.f, 0.f, 0.f};
    if (wave == 0) {
        #pragma unroll
        for (int g = 0; g < 4; ++g)
            #pragma unroll
            for (int j = 0; j < 4; ++j)
                bias_r[g][j] = bias[g * HID + bk * 8 + ju + j];
    }

    // bias-init both accumulator buffers (cells [row<32][col<32])
    for (int idx = tid; idx < 2 * 1024; idx += 512) {
        const int bsel = idx >> 10, cell = idx & 1023;
        const int row = cell >> 5, col = cell & 31;
        red[bsel][row * REDSTR + col] = bias[(col >> 3) * HID + bk * 8 + (col & 7)];
    }
    const int* myflag = flags + (sl * 32 + (lane & 31)) * FLAGSTR;
    __syncthreads();

    // ---- prologue: gates(0) adds into red[0] ----
    {
        const floatx4 zero = {0.f, 0.f, 0.f, 0.f};
        floatx4 acc[2][2] = {{zero, zero}, {zero, zero}};
        if (isG) {
            const unsigned short* xb = xT;   // t = 0 slice
            #pragma unroll
            for (int i = 0; i < 4; ++i) {
                const int k = sl * 128 + i * 32 + kq * 8;
                short8 a0 = *(const short8*)(xb + lrow * DIN + k);
                short8 a1 = *(const short8*)(xb + (lrow + 16) * DIN + k);
                acc[0][0] = MFMA16(a0, wb[i][0], acc[0][0]);
                acc[0][1] = MFMA16(a0, wb[i][1], acc[0][1]);
                acc[1][0] = MFMA16(a1, wb[i][0], acc[1][0]);
                acc[1][1] = MFMA16(a1, wb[i][1], acc[1][1]);
            }
        } else {
            floatx4 ha[8][2];
            #pragma unroll
            for (int i = 0; i < 8; ++i) {
                const int p = sl * 32 + i * 4 + kq;
                ha[i][0] = coh_load16(hbuf + p * 256 + lrow * 8);
                ha[i][1] = coh_load16(hbuf + p * 256 + (lrow + 16) * 8);
            }
            wait_vm0();
            __builtin_amdgcn_sched_barrier(0);
            #pragma unroll
            for (int i = 0; i < 8; ++i) {
                short8 a0 = __builtin_bit_cast(short8, ha[i][0]);
                short8 a1 = __builtin_bit_cast(short8, ha[i][1]);
                acc[0][0] = MFMA16(a0, wb[i][0], acc[0][0]);
                acc[0][1] = MFMA16(a0, wb[i][1], acc[0][1]);
                acc[1][0] = MFMA16(a1, wb[i][0], acc[1][0]);
                acc[1][1] = MFMA16(a1, wb[i][1], acc[1][1]);
            }
        }
        #pragma unroll
        for (int mt = 0; mt < 2; ++mt)
            #pragma unroll
            for (int nt = 0; nt < 2; ++nt)
                #pragma unroll
                for (int r = 0; r < 4; ++r)
                    lds_add(&red[0][(mt * 16 + kq * 4 + r) * REDSTR + nt * 16 + lrow],
                            acc[mt][nt][r]);
    }

    // prefetch x(1) fragments for iteration 0 (G waves)
    floatx4 xa[4][2];
    if (isG) {
        const unsigned short* xb = xT + (size_t)1 * (BATCH * DIN);
        #pragma unroll
        for (int i = 0; i < 4; ++i) {
            const int k = sl * 128 + i * 32 + kq * 8;
            xa[i][0] = *(const floatx4*)(xb + lrow * DIN + k);
            xa[i][1] = *(const floatx4*)(xb + (lrow + 16) * DIN + k);
        }
    }

    for (int t = 0; t < T_STEPS; ++t) {
        __syncthreads();    // A(t): red[t&1] complete (all waves' adds visible)
        float* rc = &red[t & 1][0];
        float* rn = &red[(t + 1) & 1][0];

        if (wave == 0) {
            __builtin_amdgcn_s_setprio(1);
            // gates for 4 outputs: 16 ds_reads (2-way max bank aliasing = free)
            float rv[4][4];
            #pragma unroll
            for (int g = 0; g < 4; ++g)
                #pragma unroll
                for (int j = 0; j < 4; ++j)
                    rv[g][j] = rc[pb * REDSTR + g * 8 + ju + j];
            float hn[4];
            #pragma unroll
            for (int j = 0; j < 4; ++j) {
                const float fg = sigf(rv[0][j]);
                const float ig = sigf(rv[1][j]);
                const float og = sigf(rv[2][j]);
                const float gg = tanh_fast(rv[3][j]);
                c_st[j] = fg * c_st[j] + ig * gg;
                hn[j] = og * tanh_fast(c_st[j]);
            }
            if (t + 1 < T_STEPS) {
                uint2_ hv;
                hv.x = (unsigned)f2bf(hn[0]) | ((unsigned)f2bf(hn[1]) << 16);
                hv.y = (unsigned)f2bf(hn[2]) | ((unsigned)f2bf(hn[3]) << 16);
                coh_store8(hbuf + (size_t)((t + 1) & 1) * (NBLK * 256)
                                + bk * 256 + pb * 8 + (lane >> 5) * 4, hv);
                wait_vm0();    // publish acked at L3
                if (lane == 0) coh_store4(flags + bk * FLAGSTR, t + 1);
            }
            __builtin_amdgcn_s_setprio(0);
            // off critical path: re-init rc with bias for reuse at t+1; out store
            #pragma unroll
            for (int g = 0; g < 4; ++g)
                #pragma unroll
                for (int j = 0; j < 4; ++j)
                    rc[pb * REDSTR + g * 8 + ju + j] = bias_r[g][j];
            floatx4 ov = {hn[0], hn[1], hn[2], hn[3]};
            *(floatx4*)(out + (size_t)pb * (T_STEPS * HID) + (size_t)t * HID
                        + bk * 8 + ju) = ov;
        }

        if (t + 1 >= T_STEPS) break;   // uniform

        const floatx4 zero = {0.f, 0.f, 0.f, 0.f};
        floatx4 acc[2][2] = {{zero, zero}, {zero, zero}};
        if (isG) {
            // x-part of gates(t+1) from prefetched regs (shadow of handshake)
            #pragma unroll
            for (int i = 0; i < 4; ++i) {
                short8 a0 = __builtin_bit_cast(short8, xa[i][0]);
                short8 a1 = __builtin_bit_cast(short8, xa[i][1]);
                acc[0][0] = MFMA16(a0, wb[i][0], acc[0][0]);
                acc[0][1] = MFMA16(a0, wb[i][1], acc[0][1]);
                acc[1][0] = MFMA16(a1, wb[i][0], acc[1][0]);
                acc[1][1] = MFMA16(a1, wb[i][1], acc[1][1]);
            }
            #pragma unroll
            for (int mt = 0; mt < 2; ++mt)
                #pragma unroll
                for (int nt = 0; nt < 2; ++nt)
                    #pragma unroll
                    for (int r = 0; r < 4; ++r)
                        lds_add(&rn[(mt * 16 + kq * 4 + r) * REDSTR + nt * 16 + lrow],
                                acc[mt][nt][r]);
            if (t + 2 < T_STEPS) {
                const unsigned short* xb = xT + (size_t)(t + 2) * (BATCH * DIN);
                #pragma unroll
                for (int i = 0; i < 4; ++i) {
                    const int k = sl * 128 + i * 32 + kq * 8;
                    xa[i][0] = *(const floatx4*)(xb + lrow * DIN + k);
                    xa[i][1] = *(const floatx4*)(xb + (lrow + 16) * DIN + k);
                }
            }
        } else {
            // wait for this wave's 32 producers, then load h(t+1)
            const int tgt = t + 1;
            while (coh_load4(myflag) < tgt)
                __builtin_amdgcn_s_sleep(1);
            const unsigned short* hb = hbuf + (size_t)((t + 1) & 1) * (NBLK * 256);
            floatx4 ha[8][2];
            #pragma unroll
            for (int i = 0; i < 8; ++i) {
                const int p = sl * 32 + i * 4 + kq;
                ha[i][0] = coh_load16(hb + p * 256 + lrow * 8);
                ha[i][1] = coh_load16(hb + p * 256 + (lrow + 16) * 8);
            }
            wait_vm0();
            __builtin_amdgcn_sched_barrier(0);
            #pragma unroll
            for (int i = 0; i < 8; ++i) {
                short8 a0 = __builtin_bit_cast(short8, ha[i][0]);
                short8 a1 = __builtin_bit_cast(short8, ha[i][1]);
                acc[0][0] = MFMA16(a0, wb[i][0], acc[0][0]);
                acc[0][1] = MFMA16(a0, wb[i][1], acc[0][1]);
                acc[1][0] = MFMA16(a1, wb[i][0], acc[1][0]);
                acc[1][1] = MFMA16(a1, wb[i][1], acc[1][1]);
            }
            #pragma unroll
            for (int mt = 0; mt < 2; ++mt)
                #pragma unroll
                for (int nt = 0; nt < 2; ++nt)
                    #pragma unroll
                    for (int r = 0; r < 4; ++r)
                        lds_add(&rn[(mt * 16 + kq * 4 + r) * REDSTR + nt * 16 + lrow],
                                acc[mt][nt][r]);
        }
    }
}

extern "C" void kernel_launch(void* const* d_in, const int* in_sizes, int n_in,
                              void* d_out, int out_size, void* d_ws, size_t ws_size,
                              hipStream_t stream) {
    (void)in_sizes; (void)n_in; (void)out_size;
    const float* x      = (const float*)d_in[0];
    // d_in[1] = input_paddings (all zero, unused per reference)
    const float* kern   = (const float*)d_in[2];
    const float* bias   = (const float*)d_in[3];
    const float* h_init = (const float*)d_in[4];
    float* out = (float*)d_out;

    char* ws = (char*)d_ws;
    unsigned short* wt    = (unsigned short*)(ws);                       // 12,582,912 B
    unsigned short* xT    = (unsigned short*)(ws + 12582912);            // 33,554,432 B
    unsigned short* hbuf  = (unsigned short*)(ws + 12582912 + 33554432); //    131,072 B
    int*            flags = (int*)(ws + 12582912 + 33554432 + 131072);   //      8,192 B
    (void)ws_size;

    prep_wt<<<dim3(64 * 24), dim3(256), 0, stream>>>(kern, wt);
    prep_x<<<dim3(BATCH * T_STEPS / 2), dim3(256), 0, stream>>>(x, xT);
    init_h<<<dim3(33), dim3(256), 0, stream>>>(h_init, hbuf, flags);

    void* args[] = { &wt, &xT, &hbuf, &flags, &bias, &out };
    hipLaunchCooperativeKernel((const void*)lstm_persist, dim3(NBLK), dim3(512),
                               args, 0, stream);
}

// Round 3
// 4400.792 us; speedup vs baseline: 2.4606x; 2.4606x over previous
//
#include <hip/hip_runtime.h>

// LSTM b=32, t=1024, din=512, hid=1024. Persistent cooperative kernel:
// 128 blocks x 512 threads (8 waves), each block owns 8 hidden units.
//
// R6 = R3/R4 skeleton (multi-wave pointwise, plain LDS red writes, honest
// flags) + three independent cuts:
//  (1) per-wave publish: each G wave gathers its own 8 batches wave-locally
//      (lgkmcnt-ordered, no barrier), stores 128B sc1, acks, sets its own
//      sub-flag; 4 sub-flags packed in 16B -> consumer polls ONE dwordx4.
//      Barrier C moves off the publish path (only gates red reuse).
//  (2) weights in registers (wb[8][2] short8/wave) -> no per-step LDS W
//      reads (R3's 1.17e8 8-way-conflict source), LDS pipe freed.
//  (3) REDSTR 33->36: pointwise gather bank = 4*l3+pu (<=2-way, free);
//      was pb+col (8-way triangle).
// Waves 0-3 "G": pointwise -> publish -> out -> [C] -> x-MFMA(t+1)+prefetch.
// Waves 4-7 "H": [C] -> poll(int4) -> sc1 h-load -> h-MFMA(t+1).
// Deadlock-free: publish(t+1) sits between A(t) and C(t), behind no barrier
// that depends on remote blocks; poll(t+1) is post-C(t). Chain over t is
// strictly decreasing -> no cycle.

#define T_STEPS 1024
#define BATCH   32
#define DIN     512
#define HID     1024
#define KTOT    1536
#define NBLK    128
#define REDSTR  36            // dword row stride: bank=(4*l3+pu)%32 -> <=2-way
#define REDW    (32*REDSTR)   // 1152 dwords per slot (slot offset bank-invariant)
#define NSLOT   8
#define FLAGSTR 16            // ints per block's flag line (64B); [0..3] = sub-flags

typedef __attribute__((ext_vector_type(8))) short  short8;
typedef __attribute__((ext_vector_type(4))) float  floatx4;
typedef __attribute__((ext_vector_type(4))) int    intx4;
typedef __attribute__((ext_vector_type(4))) unsigned short ushort4_;

#define MFMA16(a,b,c) __builtin_amdgcn_mfma_f32_16x16x32_bf16(a, b, c, 0, 0, 0)

__device__ __forceinline__ unsigned short f2bf(float f) {
    unsigned u = __builtin_bit_cast(unsigned, f);
    u += 0x7FFFu + ((u >> 16) & 1u);
    return (unsigned short)(u >> 16);
}
__device__ __forceinline__ float sigf(float x) { return 1.f / (1.f + __expf(-x)); }
__device__ __forceinline__ float tanh_fast(float x) {
    float e = __expf(2.f * x);
    return 1.f - 2.f / (e + 1.f);
}

// ---- device-scope (L3 coherence point) access helpers: sc1 ----
__device__ __forceinline__ floatx4 coh_load16(const void* p) {
    floatx4 v;
    asm volatile("global_load_dwordx4 %0, %1, off sc1" : "=v"(v) : "v"(p));
    return v;
}
__device__ __forceinline__ intx4 coh_load16i(const void* p) {
    intx4 v;
    asm volatile("global_load_dwordx4 %0, %1, off sc1\n\ts_waitcnt vmcnt(0)"
                 : "=v"(v) : "v"(p) : "memory");
    return v;
}
__device__ __forceinline__ void coh_store16(void* p, short8 v) {
    asm volatile("global_store_dwordx4 %0, %1, off sc1" :: "v"(p), "v"(v) : "memory");
}
__device__ __forceinline__ void coh_store4(void* p, int v) {
    asm volatile("global_store_dword %0, %1, off sc1" :: "v"(p), "v"(v) : "memory");
}
__device__ __forceinline__ void wait_vm0() {
    asm volatile("s_waitcnt vmcnt(0)" ::: "memory");
}

// ---- prep: kernel [1536][4096] fp32 -> wt [4096 cols][1536 k] bf16 (transposed) ----
__global__ __launch_bounds__(256) void prep_wt(const float* __restrict__ kern,
                                               unsigned short* __restrict__ wt) {
    __shared__ unsigned short tile[64][72];
    const int c0 = (blockIdx.x & 63) * 64;
    const int k0 = (blockIdx.x >> 6) * 64;
    const int cl = threadIdx.x & 63;
    const int kg = threadIdx.x >> 6;
    #pragma unroll
    for (int i = 0; i < 16; ++i) {
        int kl = kg * 16 + i;
        tile[cl][kl] = f2bf(kern[(k0 + kl) * 4096 + c0 + cl]);
    }
    __syncthreads();
    #pragma unroll
    for (int i = 0; i < 16; ++i) {
        int cc = kg * 16 + i;
        wt[(size_t)(c0 + cc) * KTOT + k0 + cl] = tile[cc][cl];
    }
}

// ---- prep: x [32][1024][512] fp32 -> xT [1024][32][512] bf16 ----
__global__ __launch_bounds__(256) void prep_x(const float* __restrict__ x,
                                              unsigned short* __restrict__ xT) {
    const int row = blockIdx.x * 2 + (threadIdx.x >> 7);
    const int l   = threadIdx.x & 127;
    const int b = row >> 10, t = row & 1023;
    float4 v = ((const float4*)(x + (size_t)row * DIN))[l];
    ushort4_ o;
    o.x = f2bf(v.x); o.y = f2bf(v.y); o.z = f2bf(v.z); o.w = f2bf(v.w);
    *(ushort4_*)(xT + ((size_t)t * BATCH + b) * DIN + l * 4) = o;
}

// ---- prep: h0 -> hbuf[0] per-block layout [blk][batch][unit]; zero ALL flags ----
__global__ __launch_bounds__(256) void init_h(const float* __restrict__ h_init,
                                              unsigned short* __restrict__ hbuf,
                                              int* __restrict__ flags) {
    if (blockIdx.x == 32) {
        for (int i = threadIdx.x; i < NBLK * FLAGSTR; i += 256) flags[i] = 0;
        return;
    }
    const int p0 = blockIdx.x * 4;
    const int u = threadIdx.x & 7;
    #pragma unroll
    for (int j = 0; j < 4; ++j) {
        const int p = p0 + j;
        hbuf[p * 256 + threadIdx.x] = f2bf(h_init[p * 8 + u]);
    }
}

// ---- persistent LSTM ----
__global__ __launch_bounds__(512, 2) void lstm_persist(
    const unsigned short* __restrict__ wt,   // [4096][1536] bf16
    const unsigned short* __restrict__ xT,   // [1024][32][512] bf16
    unsigned short* __restrict__ hbuf,       // [2][128 blk][32 b][8 u] bf16
    int* __restrict__ flags,                 // [128*FLAGSTR]; [bk*16+w] sub-flags
    const float* __restrict__ bias,          // [4096]
    float* __restrict__ out)                 // [32][1024][1024] fp32
{
    __shared__ float red[NSLOT][REDW];             // 36,864 B
    __shared__ __align__(16) unsigned short hLDS[256];  // per-wave 128B regions

    const int bk   = blockIdx.x;
    const int tid  = threadIdx.x;
    const int wave = tid >> 6;
    const int lane = tid & 63;
    const int lrow = lane & 15;
    const int kq   = lane >> 4;
    const bool isG = wave < 4;
    const int  sl  = wave & 3;

    // ---- persistent weight fragments in registers (constant across t) ----
    short8 wb[8][2];
    if (isG) {
        #pragma unroll
        for (int i = 0; i < 4; ++i) {
            const int k = sl * 128 + i * 32 + kq * 8;
            #pragma unroll
            for (int c = 0; c < 2; ++c) {
                const int cl = lrow + c * 16;
                const int gcol = (cl >> 3) * HID + bk * 8 + (cl & 7);
                wb[i][c] = *(const short8*)(wt + (size_t)gcol * KTOT + k);
            }
        }
    } else {
        #pragma unroll
        for (int i = 0; i < 8; ++i) {
            const int k = 512 + sl * 256 + i * 32 + kq * 8;
            #pragma unroll
            for (int c = 0; c < 2; ++c) {
                const int cl = lrow + c * 16;
                const int gcol = (cl >> 3) * HID + bk * 8 + (cl & 7);
                wb[i][c] = *(const short8*)(wt + (size_t)gcol * KTOT + k);
            }
        }
    }

    // pointwise mapping (tid<256 <=> G waves): (batch pb, unit pu)
    const int pb = tid >> 3;
    const int pu = tid & 7;
    float bias_r[4];
    float c_state = 0.f;
    if (tid < 256) {
        #pragma unroll
        for (int g = 0; g < 4; ++g) bias_r[g] = bias[g * HID + bk * 8 + pu];
    }

    // H wave sl polls producers [sl*32, sl*32+32): 2 lanes/flag, int4 per poll
    const int* myflag = flags + (sl * 32 + (lane & 31)) * FLAGSTR;

    floatx4 xa[4][2];

    // ---- prologue: red slots for t=0 ----
    {
        const floatx4 zero = {0.f, 0.f, 0.f, 0.f};
        floatx4 acc[2][2] = {{zero, zero}, {zero, zero}};
        if (isG) {
            const unsigned short* xb = xT;   // t = 0
            #pragma unroll
            for (int i = 0; i < 4; ++i) {
                const int k = sl * 128 + i * 32 + kq * 8;
                short8 a0 = *(const short8*)(xb + lrow * DIN + k);
                short8 a1 = *(const short8*)(xb + (lrow + 16) * DIN + k);
                acc[0][0] = MFMA16(a0, wb[i][0], acc[0][0]);
                acc[0][1] = MFMA16(a0, wb[i][1], acc[0][1]);
                acc[1][0] = MFMA16(a1, wb[i][0], acc[1][0]);
                acc[1][1] = MFMA16(a1, wb[i][1], acc[1][1]);
            }
            // prefetch xa(1)
            const unsigned short* xn = xT + (size_t)1 * (BATCH * DIN);
            #pragma unroll
            for (int i = 0; i < 4; ++i) {
                const int k = sl * 128 + i * 32 + kq * 8;
                xa[i][0] = *(const floatx4*)(xn + lrow * DIN + k);
                xa[i][1] = *(const floatx4*)(xn + (lrow + 16) * DIN + k);
            }
        } else {
            floatx4 ha[8][2];
            #pragma unroll
            for (int i = 0; i < 8; ++i) {
                const int p = sl * 32 + i * 4 + kq;
                ha[i][0] = coh_load16(hbuf + p * 256 + lrow * 8);
                ha[i][1] = coh_load16(hbuf + p * 256 + (lrow + 16) * 8);
            }
            wait_vm0();
            __builtin_amdgcn_sched_barrier(0);
            #pragma unroll
            for (int i = 0; i < 8; ++i) {
                short8 a0 = __builtin_bit_cast(short8, ha[i][0]);
                short8 a1 = __builtin_bit_cast(short8, ha[i][1]);
                acc[0][0] = MFMA16(a0, wb[i][0], acc[0][0]);
                acc[0][1] = MFMA16(a0, wb[i][1], acc[0][1]);
                acc[1][0] = MFMA16(a1, wb[i][0], acc[1][0]);
                acc[1][1] = MFMA16(a1, wb[i][1], acc[1][1]);
            }
        }
        #pragma unroll
        for (int mt = 0; mt < 2; ++mt)
            #pragma unroll
            for (int nt = 0; nt < 2; ++nt)
                #pragma unroll
                for (int r = 0; r < 4; ++r)
                    red[wave][(mt * 16 + kq * 4 + r) * REDSTR + nt * 16 + lrow]
                        = acc[mt][nt][r];
    }

    for (int t = 0; t < T_STEPS; ++t) {
        __syncthreads();    // A(t): red slots for t complete

        if (tid < 256) {
            // gather: bank = (4*(lane>>3) + pu)%32 -> <=2-way (free)
            float gv[4];
            #pragma unroll
            for (int g = 0; g < 4; ++g) {
                float s = bias_r[g];
                #pragma unroll
                for (int w = 0; w < NSLOT; ++w)
                    s += red[w][pb * REDSTR + g * 8 + pu];
                gv[g] = s;
            }
            const float fg = sigf(gv[0]);
            const float ig = sigf(gv[1]);
            const float og = sigf(gv[2]);
            const float gg = tanh_fast(gv[3]);
            c_state = fg * c_state + ig * gg;
            const float hn = og * tanh_fast(c_state);

            if (t + 1 < T_STEPS) {
                // per-wave publish: gather own 8 batches wave-locally, no barrier
                hLDS[tid] = f2bf(hn);
                asm volatile("s_waitcnt lgkmcnt(0)" ::: "memory");
                if (lane < 8) {
                    short8 v = *(const short8*)(hLDS + wave * 64 + lane * 8);
                    coh_store16(hbuf + (size_t)((t + 1) & 1) * (NBLK * 256)
                                     + bk * 256 + (wave * 8 + lane) * 8, v);
                }
                wait_vm0();    // this wave's 128B acked at L3
                if (lane == 0)
                    coh_store4(flags + bk * FLAGSTR + wave, t + 1);
            }
            // off critical path
            out[(size_t)pb * (T_STEPS * HID) + (size_t)t * HID + bk * 8 + pu] = hn;
        }

        if (t + 1 == T_STEPS) break;   // uniform

        __syncthreads();    // C(t): red reads done -> slots reusable (shadowed)

        const floatx4 zero = {0.f, 0.f, 0.f, 0.f};
        floatx4 acc[2][2] = {{zero, zero}, {zero, zero}};
        if (isG) {
            // x-part of gates(t+1) from prefetched regs (handshake shadow)
            #pragma unroll
            for (int i = 0; i < 4; ++i) {
                short8 a0 = __builtin_bit_cast(short8, xa[i][0]);
                short8 a1 = __builtin_bit_cast(short8, xa[i][1]);
                acc[0][0] = MFMA16(a0, wb[i][0], acc[0][0]);
                acc[0][1] = MFMA16(a0, wb[i][1], acc[0][1]);
                acc[1][0] = MFMA16(a1, wb[i][0], acc[1][0]);
                acc[1][1] = MFMA16(a1, wb[i][1], acc[1][1]);
            }
            if (t + 2 < T_STEPS) {
                const unsigned short* xn = xT + (size_t)(t + 2) * (BATCH * DIN);
                #pragma unroll
                for (int i = 0; i < 4; ++i) {
                    const int k = sl * 128 + i * 32 + kq * 8;
                    xa[i][0] = *(const floatx4*)(xn + lrow * DIN + k);
                    xa[i][1] = *(const floatx4*)(xn + (lrow + 16) * DIN + k);
                }
            }
        } else {
            // wait for 32 producers' sub-flags (one dwordx4 per poll)
            const int tgt = t + 1;
            while (true) {
                intx4 f = coh_load16i(myflag);
                if (f.x >= tgt && f.y >= tgt && f.z >= tgt && f.w >= tgt) break;
                __builtin_amdgcn_s_sleep(1);
            }
            const unsigned short* hb = hbuf + (size_t)((t + 1) & 1) * (NBLK * 256);
            floatx4 ha[8][2];
            #pragma unroll
            for (int i = 0; i < 8; ++i) {
                const int p = sl * 32 + i * 4 + kq;
                ha[i][0] = coh_load16(hb + p * 256 + lrow * 8);
                ha[i][1] = coh_load16(hb + p * 256 + (lrow + 16) * 8);
            }
            wait_vm0();
            __builtin_amdgcn_sched_barrier(0);
            #pragma unroll
            for (int i = 0; i < 8; ++i) {
                short8 a0 = __builtin_bit_cast(short8, ha[i][0]);
                short8 a1 = __builtin_bit_cast(short8, ha[i][1]);
                acc[0][0] = MFMA16(a0, wb[i][0], acc[0][0]);
                acc[0][1] = MFMA16(a0, wb[i][1], acc[0][1]);
                acc[1][0] = MFMA16(a1, wb[i][0], acc[1][0]);
                acc[1][1] = MFMA16(a1, wb[i][1], acc[1][1]);
            }
        }
        // red slot writes for t+1: bank = (16*kq + lrow)%32 -> 2-way (free)
        #pragma unroll
        for (int mt = 0; mt < 2; ++mt)
            #pragma unroll
            for (int nt = 0; nt < 2; ++nt)
                #pragma unroll
                for (int r = 0; r < 4; ++r)
                    red[wave][(mt * 16 + kq * 4 + r) * REDSTR + nt * 16 + lrow]
                        = acc[mt][nt][r];
    }
}

extern "C" void kernel_launch(void* const* d_in, const int* in_sizes, int n_in,
                              void* d_out, int out_size, void* d_ws, size_t ws_size,
                              hipStream_t stream) {
    (void)in_sizes; (void)n_in; (void)out_size;
    const float* x      = (const float*)d_in[0];
    // d_in[1] = input_paddings (all zero, unused per reference)
    const float* kern   = (const float*)d_in[2];
    const float* bias   = (const float*)d_in[3];
    const float* h_init = (const float*)d_in[4];
    float* out = (float*)d_out;

    char* ws = (char*)d_ws;
    unsigned short* wt    = (unsigned short*)(ws);                       // 12,582,912 B
    unsigned short* xT    = (unsigned short*)(ws + 12582912);            // 33,554,432 B
    unsigned short* hbuf  = (unsigned short*)(ws + 12582912 + 33554432); //    131,072 B
    int*            flags = (int*)(ws + 12582912 + 33554432 + 131072);   //      8,192 B
    (void)ws_size;

    prep_wt<<<dim3(64 * 24), dim3(256), 0, stream>>>(kern, wt);
    prep_x<<<dim3(BATCH * T_STEPS / 2), dim3(256), 0, stream>>>(x, xT);
    init_h<<<dim3(33), dim3(256), 0, stream>>>(h_init, hbuf, flags);

    void* args[] = { &wt, &xT, &hbuf, &flags, &bias, &out };
    hipLaunchCooperativeKernel((const void*)lstm_persist, dim3(NBLK), dim3(512),
                               args, 0, stream);
}